// Round 12
// baseline (90.346 us; speedup 1.0000x reference)
//
#include <hip/hip_runtime.h>
#include <math.h>

// Problem constants (match reference)
constexpr int Bn = 4, Cn = 12, Hn = 256, Wn = 256;
constexpr int HWn  = Hn * Wn;        // 65536
constexpr int NPIX = Bn * HWn;       // 262144
constexpr int NPLANE = Bn * Cn;      // 48 (b,c) planes
constexpr int NMASK = 2 * NPLANE;    // 96 masks (48 pred + 48 target)
constexpr int NJOB  = 2 * NMASK;     // 192 EDT jobs (edt(mask), edt(~mask))
constexpr float LARGEf = 1.0e6f;
constexpr unsigned short SENT = 65535;

// fgflags layout: [0..3] = pred fg bitmask per batch (bit c), [4..7] = tgt fg

// ---------------------------------------------------------------------------
// Kernel A: per-pixel softmax -> bit-packed masks word (bits 0..11 pred>0.5,
// bits 12..23 target one-hot), err = (prob-onehot)^2 per channel, CE partial
// per wave, per-wave OR word plain-stored (no contended atomics).
// ---------------------------------------------------------------------------
__global__ void masks_kernel(const float* __restrict__ pred,
                             const int* __restrict__ target,
                             unsigned int* __restrict__ maskw,
                             float* __restrict__ err,
                             unsigned int* __restrict__ blockOr,
                             double* __restrict__ cepart) {
    int pix = blockIdx.x * blockDim.x + threadIdx.x;   // grid = NPIX exactly
    int b = pix >> 16;            // / HW (each block lies within one b)
    int p = pix & (HWn - 1);
    float v[Cn];
    float mx = -3.4e38f;
#pragma unroll
    for (int c = 0; c < Cn; ++c) {
        v[c] = pred[(size_t)(b * Cn + c) * HWn + p];
        mx = fmaxf(mx, v[c]);
    }
    int t = target[pix];
    float raw_t = 0.f, s = 0.f;
#pragma unroll
    for (int c = 0; c < Cn; ++c) {
        if (c == t) raw_t = v[c];
        v[c] = expf(v[c] - mx);
        s += v[c];
    }
    unsigned word = 1u << (Cn + t);   // target one-hot bit
#pragma unroll
    for (int c = 0; c < Cn; ++c) {
        float prob = v[c] / s;
        int pb = (prob > 0.5f) ? 1 : 0;
        word |= (unsigned)pb << c;
        float oh = (c == t) ? 1.0f : 0.0f;
        float d = prob - oh;
        err[(size_t)(b * Cn + c) * HWn + p] = d * d;
    }
    maskw[pix] = word;
    float logp_t = raw_t - mx - logf(s);

    // wave-level OR + CE sum (no barriers), one plain store per wave
    unsigned worw = word;
    for (int o = 32; o > 0; o >>= 1) worw |= __shfl_down(worw, o, 64);
    double ced = (double)logp_t;
    for (int o = 32; o > 0; o >>= 1) ced += __shfl_down(ced, o, 64);
    int lane = threadIdx.x & 63, wv = threadIdx.x >> 6;
    if (lane == 0) {
        blockOr[blockIdx.x * 4 + wv] = worw;   // plain store, zero contention
        cepart[blockIdx.x * 4 + wv] = ced;
    }
}

__device__ __forceinline__ int mask_has_fg(const unsigned int* fgflags, int m) {
    int mm = (m < NPLANE) ? m : m - NPLANE;
    int b = mm / Cn, c = mm % Cn;
    unsigned fg = (m < NPLANE) ? fgflags[b] : fgflags[4 + b];
    return (fg >> c) & 1;
}

// ---------------------------------------------------------------------------
// Kernel C: segmented column pass (ungated; rowpass gates correctness).
// LDS distance bytes PACKED 4-per-u32 (one ds_write_b32 / ds_read_b32 per 4
// rows instead of 4 byte ops) - values bit-identical to the u8 version.
// Block NJOB*SEG does the fgflags reduction (stream order covers the dep).
// ---------------------------------------------------------------------------
constexpr int SEG  = 4;
constexpr int SEGR = Hn / SEG;   // 64
constexpr int STRw = 17;         // u32 stride per thread (17 coprime with 32 banks)

__global__ void colpass_kernel(const unsigned int* __restrict__ maskw,
                               const unsigned int* __restrict__ blockOr,
                               unsigned short* __restrict__ gcol,
                               unsigned int* __restrict__ fgflags) {
    int blk = blockIdx.x;         // 0..768
    int tid = threadIdx.x;
    int lane = tid & 63, wv = tid >> 6;
    if (blk == NJOB * SEG) {
        unsigned acc = 0;
#pragma unroll
        for (int k = 0; k < 16; ++k) acc |= blockOr[wv * 1024 + k * 64 + lane];
        for (int o = 32; o > 0; o >>= 1) acc |= __shfl_down(acc, o, 64);
        if (lane == 0) {
            fgflags[wv] = acc & 0xFFFu;
            fgflags[4 + wv] = acc >> Cn;
        }
        return;
    }
    int jb = blk >> 2;            // job 0..191
    int cg = blk & 3;             // column group
    int m  = (jb < NMASK) ? jb : jb - NMASK;
    int mm = (m < NPLANE) ? m : m - NPLANE;
    int b = mm / Cn, c = mm % Cn;
    unsigned bit = (m < NPLANE) ? (unsigned)c : (unsigned)(Cn + c);
    unsigned inv = (jb < NMASK) ? 1u : 0u;  // feature = !maskbit for edt(mask)
    int s  = wv;                  // segment 0..3 (uniform per wave)
    int jl = lane;
    int j  = cg * 64 + jl;
    int r0 = s * SEGR;
    const unsigned int* mp = maskw + (size_t)b * HWn;
    unsigned short* gp = gcol + (size_t)jb * HWn;

    __shared__ unsigned ldsF32[256 * STRw];
    __shared__ unsigned ldsB32[256 * STRw];
    __shared__ float eF[256], eB[256];

    unsigned b0 = 0, b1 = 0;
    unsigned pk = 0;
    float cd = LARGEf;
    for (int i = 0; i < SEGR; ++i) {
        unsigned w = mp[(r0 + i) * Wn + j];
        unsigned f = ((w >> bit) & 1u) ^ inv;
        if (i < 32) b0 |= f << i; else b1 |= f << (i - 32);
        cd = f ? 0.f : fminf(cd + 1.f, LARGEf);
        unsigned byte = (unsigned)fminf(cd, 255.f);   // <=63 local, or 255 sentinel
        pk |= byte << (8 * (i & 3));
        if ((i & 3) == 3) { ldsF32[tid * STRw + (i >> 2)] = pk; pk = 0; }
    }
    eF[tid] = cd;
    cd = LARGEf;
    pk = 0;
    for (int i = SEGR - 1; i >= 0; --i) {
        unsigned f = ((i < 32) ? (b0 >> i) : (b1 >> (i - 32))) & 1u;
        cd = f ? 0.f : fminf(cd + 1.f, LARGEf);
        unsigned byte = (unsigned)fminf(cd, 255.f);
        pk |= byte << (8 * (i & 3));
        if ((i & 3) == 0) { ldsB32[tid * STRw + (i >> 2)] = pk; pk = 0; }
    }
    eB[tid] = cd;
    __syncthreads();
    float x = LARGEf;                         // fwd inflow to my segment
    for (int sp = 0; sp < s; ++sp)
        x = fminf(eF[sp * 64 + jl], fminf(x + (float)SEGR, LARGEf));
    float y = LARGEf;                         // bwd inflow from below
    for (int sp = SEG - 1; sp > s; --sp)
        y = fminf(eB[sp * 64 + jl], fminf(y + (float)SEGR, LARGEf));
    for (int q = 0; q < SEGR / 4; ++q) {
        unsigned wF = ldsF32[tid * STRw + q];
        unsigned wB = ldsB32[tid * STRw + q];
#pragma unroll
        for (int b2 = 0; b2 < 4; ++b2) {
            int i = q * 4 + b2;
            unsigned uf = (wF >> (8 * b2)) & 0xFFu;
            unsigned ub = (wB >> (8 * b2)) & 0xFFu;
            float lf = (uf == 255u) ? LARGEf : (float)uf;
            float lb = (ub == 255u) ? LARGEf : (float)ub;
            float f = fminf(lf, fminf(x + (float)(i + 1), LARGEf));
            float w = fminf(lb, fminf(y + (float)(SEGR - i), LARGEf));
            float g = fminf(f, w);
            gp[(r0 + i) * Wn + j] = (g >= LARGEf) ? SENT : (unsigned short)g;
        }
    }
}

// ---------------------------------------------------------------------------
// Kernel D (v3): wave-per-row row pass, u16 LDS rows, INT-domain paired
// probes. Row staged as raw u16 clamped to 511 (real dists <=255 unchanged;
// SENT -> 511; pads 511). One aligned b32 read = two adjacent u16 probes.
// cand = g*g + d*d (int, <2^24, exact); min order-independent; m >= 511^2
// <=> no real candidate <=> reference value 1e12 -> f = 1e6 (== sqrtf(1e12f)).
// Per-group independent wave-break loops. Epilogue: f64 wave reduce.
// ---------------------------------------------------------------------------
constexpr int RPAD16 = 256;            // u16 pad elements each side
constexpr unsigned BIGI = 511u * 511u; // 261121: sentinel threshold (> max real 130561)
constexpr int NROWBLK = NMASK * Hn;    // 24576 row-jobs
constexpr int RPB = 4;                 // rows per block (one per wave)

__device__ __forceinline__ unsigned scan_one(const unsigned short* __restrict__ row,
                                             int j) {
    // row = padded row base; real element e at row[RPAD16 + e]
    const unsigned short* base = row + RPAD16;
    int pl = (j - 1) & ~1;           // left pair start (even element idx)
    int pr = (j + 1) & ~1;           // right pair start (even)
    int cL = j - pl;                 // 1 or 2
    int cR = pr - j;                 // 0 or 1
    unsigned m = 0x7FFFFFFFu;
    for (int t = 0; t < 128; ++t) {
        unsigned kmin = (unsigned)(2 * t);
        if (t > 0 && !__any(kmin * kmin < m)) break;   // all remaining cands >= (2t)^2 >= m
        unsigned wl = *(const unsigned*)(base + (pl - 2 * t));   // elems (pl-2t, pl-2t+1)
        unsigned wr = *(const unsigned*)(base + (pr + 2 * t));   // elems (pr+2t, pr+2t+1)
        unsigned dLlo = (unsigned)(cL + 2 * t);        // dist of lo u16 (elem pl-2t)
        unsigned dLhi = dLlo - 1u;                     // elem pl-2t+1
        unsigned dRlo = (unsigned)(cR + 2 * t);        // elem pr+2t
        unsigned dRhi = dRlo + 1u;                     // elem pr+2t+1
        unsigned lo = wl & 0xFFFFu, hi = wl >> 16, cand;
        cand = lo * lo + dLlo * dLlo; m = cand < m ? cand : m;
        cand = hi * hi + dLhi * dLhi; m = cand < m ? cand : m;
        lo = wr & 0xFFFFu; hi = wr >> 16;
        cand = lo * lo + dRlo * dRlo; m = cand < m ? cand : m;
        cand = hi * hi + dRhi * dRhi; m = cand < m ? cand : m;
    }
    return m;
}

__global__ void rowpass_kernel(const unsigned short* __restrict__ gcol,
                               const float* __restrict__ err,
                               const unsigned int* __restrict__ fgflags,
                               double* __restrict__ partials) {
    int blk = blockIdx.x;                 // 0..6143
    int tid = threadIdx.x;
    int lane = tid & 63, w = tid >> 6;
    int m = (blk * RPB) >> 8;             // plane (uniform: 4 rows never straddle)
    if (!mask_has_fg(fgflags, m)) {
        if (tid < RPB) partials[blk * RPB + tid] = 0.0;
        return;                           // uniform exit
    }
    int job = blk * RPB + w;              // this wave's row-job
    int i = job & (Hn - 1);               // row
    __shared__ unsigned short lds[RPB][2][2 * RPAD16 + Wn];   // 12 KB
    unsigned short* rA = lds[w][0];
    unsigned short* rB = lds[w][1];

    const unsigned short* rp = gcol + (size_t)m * HWn + i * Wn;            // edt(mask)
    const unsigned short* rq = gcol + (size_t)(m + NMASK) * HWn + i * Wn;  // edt(~mask)
    ushort4 ua = ((const ushort4*)rp)[lane];
    ushort4 ub = ((const ushort4*)rq)[lane];
    // clamp to 511: real dists (<=255) unchanged, SENT -> 511 sentinel
    ua.x = ua.x > 511 ? 511 : ua.x;  ua.y = ua.y > 511 ? 511 : ua.y;
    ua.z = ua.z > 511 ? 511 : ua.z;  ua.w = ua.w > 511 ? 511 : ua.w;
    ub.x = ub.x > 511 ? 511 : ub.x;  ub.y = ub.y > 511 ? 511 : ub.y;
    ub.z = ub.z > 511 ? 511 : ub.z;  ub.w = ub.w > 511 ? 511 : ub.w;
    ushort4 s4 = make_ushort4(511, 511, 511, 511);
    ((ushort4*)rA)[lane] = s4;            // left pad (elems -256..-1)
    ((ushort4*)rA)[64 + lane] = ua;       // data
    ((ushort4*)rA)[128 + lane] = s4;      // right pad
    ((ushort4*)rB)[lane] = s4;
    ((ushort4*)rB)[64 + lane] = ub;
    ((ushort4*)rB)[128 + lane] = s4;
    __syncthreads();                      // uniform arrival

    unsigned mA[4], mB[4];
#pragma unroll
    for (int g = 0; g < 4; ++g) mA[g] = scan_one(rA, lane + 64 * g);
#pragma unroll
    for (int g = 0; g < 4; ++g) mB[g] = scan_one(rB, lane + 64 * g);

    int ep = (m < NPLANE) ? m : m - NPLANE;
    const float* epr = err + (size_t)ep * HWn + i * Wn;
    double v = 0.0;
#pragma unroll
    for (int g = 0; g < 4; ++g) {
        float fa = (mA[g] >= BIGI) ? 1.0e6f : sqrtf((float)mA[g]);   // sqrtf(1e12f)==1e6f
        float fb = (mB[g] >= BIGI) ? 1.0e6f : sqrtf((float)mB[g]);
        float f = fa + fb;
        float e = epr[lane + 64 * g];
        v += (double)(e * (f * f));
    }
    for (int o = 32; o > 0; o >>= 1) v += __shfl_down(v, o, 64);
    if (lane == 0) partials[job] = v;
}

// ---------------------------------------------------------------------------
// Kernel F: final reduction -> scalar (1024 threads)
// ---------------------------------------------------------------------------
__global__ void final_kernel(const double* __restrict__ partials,
                             const double* __restrict__ cepart,
                             float* __restrict__ out) {
    int tid = threadIdx.x;
    double a = 0.0, ce = 0.0;
    for (int idx = tid; idx < NROWBLK; idx += 1024) a += partials[idx];
    for (int idx = tid; idx < 4096; idx += 1024) ce += cepart[idx];
    __shared__ double sa[1024], sc[1024];
    sa[tid] = a; sc[tid] = ce;
    __syncthreads();
    for (int s = 512; s > 0; s >>= 1) {
        if (tid < s) { sa[tid] += sa[tid + s]; sc[tid] += sc[tid + s]; }
        __syncthreads();
    }
    if (tid == 0) {
        double loss_sum = sa[0] / (double)NPIX;        // sum_c mean_{b,h,w}
        double cem = -sc[0] / (double)NPIX;            // ce
        double res = loss_sum / (double)Cn / (double)Bn / 3.0 + cem;
        out[0] = (float)res;
    }
}

// ---------------------------------------------------------------------------
extern "C" void kernel_launch(void* const* d_in, const int* in_sizes, int n_in,
                              void* d_out, int out_size, void* d_ws, size_t ws_size,
                              hipStream_t stream) {
    const float* pred  = (const float*)d_in[0];
    const int* target  = (const int*)d_in[1];
    float* out = (float*)d_out;
    char* ws = (char*)d_ws;

    // workspace layout (~40 MB total)
    unsigned int* maskw = (unsigned int*)ws;                         // 1 MB
    size_t off = (size_t)NPIX * 4;
    float* err = (float*)(ws + off);                                 // 12.6 MB
    off += (size_t)NPLANE * HWn * 4;
    unsigned short* gcol = (unsigned short*)(ws + off);              // 25.2 MB
    off += (size_t)NJOB * HWn * 2;
    unsigned int* fgflags = (unsigned int*)(ws + off);               // 8 u32 (pad 512)
    off += 512;
    unsigned int* blockOr = (unsigned int*)(ws + off);               // 4096*4
    off += 4096 * 4;
    double* partials = (double*)(ws + off);                          // 24576*8
    off += (size_t)NROWBLK * 8;
    double* cepart = (double*)(ws + off);                            // 4096*8

    masks_kernel<<<NPIX / 256, 256, 0, stream>>>(pred, target, maskw, err,
                                                 blockOr, cepart);
    colpass_kernel<<<NJOB * SEG + 1, 256, 0, stream>>>(maskw, blockOr, gcol, fgflags);
    rowpass_kernel<<<NROWBLK / RPB, 256, 0, stream>>>(gcol, err, fgflags, partials);
    final_kernel<<<1, 1024, 0, stream>>>(partials, cepart, out);
}

// Round 13
// 90.184 us; speedup vs baseline: 1.0018x; 1.0018x over previous
//
#include <hip/hip_runtime.h>
#include <math.h>

// Problem constants (match reference)
constexpr int Bn = 4, Cn = 12, Hn = 256, Wn = 256;
constexpr int HWn  = Hn * Wn;        // 65536
constexpr int NPIX = Bn * HWn;       // 262144
constexpr int NPLANE = Bn * Cn;      // 48 (b,c) planes
constexpr int NMASK = 2 * NPLANE;    // 96 masks (48 pred + 48 target)
constexpr int NJOB  = 2 * NMASK;     // 192 EDT jobs (edt(mask), edt(~mask))
constexpr float LARGEf = 1.0e6f;
constexpr unsigned short SENT = 65535;

// fgflags layout: [0..3] = pred fg bitmask per batch (bit c), [4..7] = tgt fg

// ---------------------------------------------------------------------------
// Kernel A: per-pixel softmax -> bit-packed masks word (bits 0..11 pred>0.5,
// bits 12..23 target one-hot), err = (prob-onehot)^2 per channel, CE partial
// per wave, per-wave OR word plain-stored (no contended atomics).
// ---------------------------------------------------------------------------
__global__ void masks_kernel(const float* __restrict__ pred,
                             const int* __restrict__ target,
                             unsigned int* __restrict__ maskw,
                             float* __restrict__ err,
                             unsigned int* __restrict__ blockOr,
                             double* __restrict__ cepart) {
    int pix = blockIdx.x * blockDim.x + threadIdx.x;   // grid = NPIX exactly
    int b = pix >> 16;            // / HW (each block lies within one b)
    int p = pix & (HWn - 1);
    float v[Cn];
    float mx = -3.4e38f;
#pragma unroll
    for (int c = 0; c < Cn; ++c) {
        v[c] = pred[(size_t)(b * Cn + c) * HWn + p];
        mx = fmaxf(mx, v[c]);
    }
    int t = target[pix];
    float raw_t = 0.f, s = 0.f;
#pragma unroll
    for (int c = 0; c < Cn; ++c) {
        if (c == t) raw_t = v[c];
        v[c] = expf(v[c] - mx);
        s += v[c];
    }
    unsigned word = 1u << (Cn + t);   // target one-hot bit
#pragma unroll
    for (int c = 0; c < Cn; ++c) {
        float prob = v[c] / s;
        int pb = (prob > 0.5f) ? 1 : 0;
        word |= (unsigned)pb << c;
        float oh = (c == t) ? 1.0f : 0.0f;
        float d = prob - oh;
        err[(size_t)(b * Cn + c) * HWn + p] = d * d;
    }
    maskw[pix] = word;
    float logp_t = raw_t - mx - logf(s);

    // wave-level OR + CE sum (no barriers), one plain store per wave
    unsigned worw = word;
    for (int o = 32; o > 0; o >>= 1) worw |= __shfl_down(worw, o, 64);
    double ced = (double)logp_t;
    for (int o = 32; o > 0; o >>= 1) ced += __shfl_down(ced, o, 64);
    int lane = threadIdx.x & 63, wv = threadIdx.x >> 6;
    if (lane == 0) {
        blockOr[blockIdx.x * 4 + wv] = worw;   // plain store, zero contention
        cepart[blockIdx.x * 4 + wv] = ced;
    }
}

__device__ __forceinline__ int mask_has_fg(const unsigned int* fgflags, int m) {
    int mm = (m < NPLANE) ? m : m - NPLANE;
    int b = mm / Cn, c = mm % Cn;
    unsigned fg = (m < NPLANE) ? fgflags[b] : fgflags[4 + b];
    return (fg >> c) & 1;
}

// ---------------------------------------------------------------------------
// Kernel C: segmented column pass (ungated; rowpass gates correctness).
// LDS distance bytes packed 4-per-u32. Block NJOB*SEG does the fgflags
// reduction (stream order covers the dep).
// ---------------------------------------------------------------------------
constexpr int SEG  = 4;
constexpr int SEGR = Hn / SEG;   // 64
constexpr int STRw = 17;         // u32 stride per thread (17 coprime with 32 banks)

__global__ void colpass_kernel(const unsigned int* __restrict__ maskw,
                               const unsigned int* __restrict__ blockOr,
                               unsigned short* __restrict__ gcol,
                               unsigned int* __restrict__ fgflags) {
    int blk = blockIdx.x;         // 0..768
    int tid = threadIdx.x;
    int lane = tid & 63, wv = tid >> 6;
    if (blk == NJOB * SEG) {
        unsigned acc = 0;
#pragma unroll
        for (int k = 0; k < 16; ++k) acc |= blockOr[wv * 1024 + k * 64 + lane];
        for (int o = 32; o > 0; o >>= 1) acc |= __shfl_down(acc, o, 64);
        if (lane == 0) {
            fgflags[wv] = acc & 0xFFFu;
            fgflags[4 + wv] = acc >> Cn;
        }
        return;
    }
    int jb = blk >> 2;            // job 0..191
    int cg = blk & 3;             // column group
    int m  = (jb < NMASK) ? jb : jb - NMASK;
    int mm = (m < NPLANE) ? m : m - NPLANE;
    int b = mm / Cn, c = mm % Cn;
    unsigned bit = (m < NPLANE) ? (unsigned)c : (unsigned)(Cn + c);
    unsigned inv = (jb < NMASK) ? 1u : 0u;  // feature = !maskbit for edt(mask)
    int s  = wv;                  // segment 0..3 (uniform per wave)
    int jl = lane;
    int j  = cg * 64 + jl;
    int r0 = s * SEGR;
    const unsigned int* mp = maskw + (size_t)b * HWn;
    unsigned short* gp = gcol + (size_t)jb * HWn;

    __shared__ unsigned ldsF32[256 * STRw];
    __shared__ unsigned ldsB32[256 * STRw];
    __shared__ float eF[256], eB[256];

    unsigned b0 = 0, b1 = 0;
    unsigned pk = 0;
    float cd = LARGEf;
    for (int i = 0; i < SEGR; ++i) {
        unsigned w = mp[(r0 + i) * Wn + j];
        unsigned f = ((w >> bit) & 1u) ^ inv;
        if (i < 32) b0 |= f << i; else b1 |= f << (i - 32);
        cd = f ? 0.f : fminf(cd + 1.f, LARGEf);
        unsigned byte = (unsigned)fminf(cd, 255.f);   // <=63 local, or 255 sentinel
        pk |= byte << (8 * (i & 3));
        if ((i & 3) == 3) { ldsF32[tid * STRw + (i >> 2)] = pk; pk = 0; }
    }
    eF[tid] = cd;
    cd = LARGEf;
    pk = 0;
    for (int i = SEGR - 1; i >= 0; --i) {
        unsigned f = ((i < 32) ? (b0 >> i) : (b1 >> (i - 32))) & 1u;
        cd = f ? 0.f : fminf(cd + 1.f, LARGEf);
        unsigned byte = (unsigned)fminf(cd, 255.f);
        pk |= byte << (8 * (i & 3));
        if ((i & 3) == 0) { ldsB32[tid * STRw + (i >> 2)] = pk; pk = 0; }
    }
    eB[tid] = cd;
    __syncthreads();
    float x = LARGEf;                         // fwd inflow to my segment
    for (int sp = 0; sp < s; ++sp)
        x = fminf(eF[sp * 64 + jl], fminf(x + (float)SEGR, LARGEf));
    float y = LARGEf;                         // bwd inflow from below
    for (int sp = SEG - 1; sp > s; --sp)
        y = fminf(eB[sp * 64 + jl], fminf(y + (float)SEGR, LARGEf));
    for (int q = 0; q < SEGR / 4; ++q) {
        unsigned wF = ldsF32[tid * STRw + q];
        unsigned wB = ldsB32[tid * STRw + q];
#pragma unroll
        for (int b2 = 0; b2 < 4; ++b2) {
            int i = q * 4 + b2;
            unsigned uf = (wF >> (8 * b2)) & 0xFFu;
            unsigned ub = (wB >> (8 * b2)) & 0xFFu;
            float lf = (uf == 255u) ? LARGEf : (float)uf;
            float lb = (ub == 255u) ? LARGEf : (float)ub;
            float f = fminf(lf, fminf(x + (float)(i + 1), LARGEf));
            float w = fminf(lb, fminf(y + (float)(SEGR - i), LARGEf));
            float g = fminf(f, w);
            gp[(r0 + i) * Wn + j] = (g >= LARGEf) ? SENT : (unsigned short)g;
        }
    }
}

// ---------------------------------------------------------------------------
// Kernel D (v4): wave-per-row row pass; u16 LDS rows; FUSED 4-group loop with
// b64 probes. Per iteration: 8 INDEPENDENT ds_read_b64 (4 groups x 2 sides),
// each = 4 u16 elements; per-thread register break (no wave votes, no
// latency chain per read). Left blocks cover elements <= Lb+3, right blocks
// >= Lb+4: every element covered exactly once per scan with correct d^2
// (negative diffs squared). cand = g*g + d*d in int (<2^24, exact).
// m >= 511^2 <=> all-sentinel <=> reference value 1e12 -> f = 1e6.
// ---------------------------------------------------------------------------
constexpr int RPAD16 = 256;            // u16 pad elements each side
constexpr unsigned BIGI = 511u * 511u; // 261121 (> max real cand ~131589)
constexpr int NROWBLK = NMASK * Hn;    // 24576 row-jobs
constexpr int RPB = 4;                 // rows per block (one per wave)

__device__ __forceinline__ void scan4_b64(const unsigned short* __restrict__ row,
                                          int lane, unsigned m[4]) {
    const unsigned short* base = row + RPAD16;
    const int c0 = lane & 3;
    const int Lb = lane & ~3;          // group g adds +64g (parity/c0 identical)
    for (int t = 0; t < 64; ++t) {
        if (t > 0) {
            int dL = 4 * t - 3 + c0;   // min |d| among remaining left elems
            int dR = 4 * t + 4 - c0;   // min |d| among remaining right elems
            int dm = dL < dR ? dL : dR;
            unsigned mx = m[0] > m[1] ? m[0] : m[1];
            unsigned mx2 = m[2] > m[3] ? m[2] : m[3];
            mx = mx > mx2 ? mx : mx2;
            if ((unsigned)(dm * dm) >= mx) break;
        }
        unsigned dl[4], dr[4];
#pragma unroll
        for (int i2 = 0; i2 < 4; ++i2) {
            int dv = c0 + 4 * t - i2;          // left elem i2: d = j - e
            dl[i2] = (unsigned)(dv * dv);
            int dv2 = 4 + 4 * t + i2 - c0;     // right elem i2
            dr[i2] = (unsigned)(dv2 * dv2);
        }
#pragma unroll
        for (int g = 0; g < 4; ++g) {
            uint2 wl = *(const uint2*)(base + Lb + 64 * g - 4 * t);
            uint2 wr = *(const uint2*)(base + Lb + 4 + 64 * g + 4 * t);
            unsigned e0 = wl.x & 0xFFFFu, e1 = wl.x >> 16;
            unsigned e2 = wl.y & 0xFFFFu, e3 = wl.y >> 16;
            unsigned c;
            c = e0 * e0 + dl[0]; m[g] = c < m[g] ? c : m[g];
            c = e1 * e1 + dl[1]; m[g] = c < m[g] ? c : m[g];
            c = e2 * e2 + dl[2]; m[g] = c < m[g] ? c : m[g];
            c = e3 * e3 + dl[3]; m[g] = c < m[g] ? c : m[g];
            e0 = wr.x & 0xFFFFu; e1 = wr.x >> 16;
            e2 = wr.y & 0xFFFFu; e3 = wr.y >> 16;
            c = e0 * e0 + dr[0]; m[g] = c < m[g] ? c : m[g];
            c = e1 * e1 + dr[1]; m[g] = c < m[g] ? c : m[g];
            c = e2 * e2 + dr[2]; m[g] = c < m[g] ? c : m[g];
            c = e3 * e3 + dr[3]; m[g] = c < m[g] ? c : m[g];
        }
    }
}

__global__ void rowpass_kernel(const unsigned short* __restrict__ gcol,
                               const float* __restrict__ err,
                               const unsigned int* __restrict__ fgflags,
                               double* __restrict__ partials) {
    int blk = blockIdx.x;                 // 0..6143
    int tid = threadIdx.x;
    int lane = tid & 63, w = tid >> 6;
    int m = (blk * RPB) >> 8;             // plane (uniform: 4 rows never straddle)
    if (!mask_has_fg(fgflags, m)) {
        if (tid < RPB) partials[blk * RPB + tid] = 0.0;
        return;                           // uniform exit
    }
    int job = blk * RPB + w;              // this wave's row-job
    int i = job & (Hn - 1);               // row
    __shared__ __attribute__((aligned(16))) unsigned short lds[RPB][2][2 * RPAD16 + Wn];
    unsigned short* rA = lds[w][0];
    unsigned short* rB = lds[w][1];

    const unsigned short* rp = gcol + (size_t)m * HWn + i * Wn;            // edt(mask)
    const unsigned short* rq = gcol + (size_t)(m + NMASK) * HWn + i * Wn;  // edt(~mask)
    ushort4 ua = ((const ushort4*)rp)[lane];
    ushort4 ub = ((const ushort4*)rq)[lane];
    // clamp to 511: real dists (<=255) unchanged, SENT -> 511 sentinel
    ua.x = ua.x > 511 ? 511 : ua.x;  ua.y = ua.y > 511 ? 511 : ua.y;
    ua.z = ua.z > 511 ? 511 : ua.z;  ua.w = ua.w > 511 ? 511 : ua.w;
    ub.x = ub.x > 511 ? 511 : ub.x;  ub.y = ub.y > 511 ? 511 : ub.y;
    ub.z = ub.z > 511 ? 511 : ub.z;  ub.w = ub.w > 511 ? 511 : ub.w;
    ushort4 s4 = make_ushort4(511, 511, 511, 511);
    ((ushort4*)rA)[lane] = s4;            // left pad (elems -256..-1)
    ((ushort4*)rA)[64 + lane] = ua;       // data
    ((ushort4*)rA)[128 + lane] = s4;      // right pad
    ((ushort4*)rB)[lane] = s4;
    ((ushort4*)rB)[64 + lane] = ub;
    ((ushort4*)rB)[128 + lane] = s4;
    __syncthreads();                      // uniform arrival

    unsigned mA[4] = {0x7FFFFFFFu, 0x7FFFFFFFu, 0x7FFFFFFFu, 0x7FFFFFFFu};
    unsigned mB[4] = {0x7FFFFFFFu, 0x7FFFFFFFu, 0x7FFFFFFFu, 0x7FFFFFFFu};
    scan4_b64(rA, lane, mA);
    scan4_b64(rB, lane, mB);

    int ep = (m < NPLANE) ? m : m - NPLANE;
    const float* epr = err + (size_t)ep * HWn + i * Wn;
    double v = 0.0;
#pragma unroll
    for (int g = 0; g < 4; ++g) {
        float fa = (mA[g] >= BIGI) ? 1.0e6f : sqrtf((float)mA[g]);   // sqrtf(1e12f)==1e6f
        float fb = (mB[g] >= BIGI) ? 1.0e6f : sqrtf((float)mB[g]);
        float f = fa + fb;
        float e = epr[lane + 64 * g];
        v += (double)(e * (f * f));
    }
    for (int o = 32; o > 0; o >>= 1) v += __shfl_down(v, o, 64);
    if (lane == 0) partials[job] = v;
}

// ---------------------------------------------------------------------------
// Kernel F: final reduction -> scalar (1024 threads)
// ---------------------------------------------------------------------------
__global__ void final_kernel(const double* __restrict__ partials,
                             const double* __restrict__ cepart,
                             float* __restrict__ out) {
    int tid = threadIdx.x;
    double a = 0.0, ce = 0.0;
    for (int idx = tid; idx < NROWBLK; idx += 1024) a += partials[idx];
    for (int idx = tid; idx < 4096; idx += 1024) ce += cepart[idx];
    __shared__ double sa[1024], sc[1024];
    sa[tid] = a; sc[tid] = ce;
    __syncthreads();
    for (int s = 512; s > 0; s >>= 1) {
        if (tid < s) { sa[tid] += sa[tid + s]; sc[tid] += sc[tid + s]; }
        __syncthreads();
    }
    if (tid == 0) {
        double loss_sum = sa[0] / (double)NPIX;        // sum_c mean_{b,h,w}
        double cem = -sc[0] / (double)NPIX;            // ce
        double res = loss_sum / (double)Cn / (double)Bn / 3.0 + cem;
        out[0] = (float)res;
    }
}

// ---------------------------------------------------------------------------
extern "C" void kernel_launch(void* const* d_in, const int* in_sizes, int n_in,
                              void* d_out, int out_size, void* d_ws, size_t ws_size,
                              hipStream_t stream) {
    const float* pred  = (const float*)d_in[0];
    const int* target  = (const int*)d_in[1];
    float* out = (float*)d_out;
    char* ws = (char*)d_ws;

    // workspace layout (~40 MB total)
    unsigned int* maskw = (unsigned int*)ws;                         // 1 MB
    size_t off = (size_t)NPIX * 4;
    float* err = (float*)(ws + off);                                 // 12.6 MB
    off += (size_t)NPLANE * HWn * 4;
    unsigned short* gcol = (unsigned short*)(ws + off);              // 25.2 MB
    off += (size_t)NJOB * HWn * 2;
    unsigned int* fgflags = (unsigned int*)(ws + off);               // 8 u32 (pad 512)
    off += 512;
    unsigned int* blockOr = (unsigned int*)(ws + off);               // 4096*4
    off += 4096 * 4;
    double* partials = (double*)(ws + off);                          // 24576*8
    off += (size_t)NROWBLK * 8;
    double* cepart = (double*)(ws + off);                            // 4096*8

    masks_kernel<<<NPIX / 256, 256, 0, stream>>>(pred, target, maskw, err,
                                                 blockOr, cepart);
    colpass_kernel<<<NJOB * SEG + 1, 256, 0, stream>>>(maskw, blockOr, gcol, fgflags);
    rowpass_kernel<<<NROWBLK / RPB, 256, 0, stream>>>(gcol, err, fgflags, partials);
    final_kernel<<<1, 1024, 0, stream>>>(partials, cepart, out);
}

// Round 14
// 78.850 us; speedup vs baseline: 1.1458x; 1.1437x over previous
//
#include <hip/hip_runtime.h>
#include <math.h>

// Problem constants (match reference)
constexpr int Bn = 4, Cn = 12, Hn = 256, Wn = 256;
constexpr int HWn  = Hn * Wn;        // 65536
constexpr int NPIX = Bn * HWn;       // 262144
constexpr int NPLANE = Bn * Cn;      // 48 (b,c) planes
constexpr int NMASK = 2 * NPLANE;    // 96 masks (48 pred + 48 target)
constexpr int NJOB  = 2 * NMASK;     // 192 EDT jobs (edt(mask), edt(~mask))
constexpr float LARGEf = 1.0e6f;
constexpr unsigned short SENT = 65535;

// fgflags layout: [0..3] = pred fg bitmask per batch (bit c), [4..7] = tgt fg

// ---------------------------------------------------------------------------
// Kernel A: per-pixel softmax -> bit-packed masks word (bits 0..11 pred>0.5,
// bits 12..23 target one-hot), err = (prob-onehot)^2 per channel, CE partial
// per wave, per-wave OR word plain-stored (no contended atomics).
// ---------------------------------------------------------------------------
__global__ void masks_kernel(const float* __restrict__ pred,
                             const int* __restrict__ target,
                             unsigned int* __restrict__ maskw,
                             float* __restrict__ err,
                             unsigned int* __restrict__ blockOr,
                             double* __restrict__ cepart) {
    int pix = blockIdx.x * blockDim.x + threadIdx.x;   // grid = NPIX exactly
    int b = pix >> 16;            // / HW (each block lies within one b)
    int p = pix & (HWn - 1);
    float v[Cn];
    float mx = -3.4e38f;
#pragma unroll
    for (int c = 0; c < Cn; ++c) {
        v[c] = pred[(size_t)(b * Cn + c) * HWn + p];
        mx = fmaxf(mx, v[c]);
    }
    int t = target[pix];
    float raw_t = 0.f, s = 0.f;
#pragma unroll
    for (int c = 0; c < Cn; ++c) {
        if (c == t) raw_t = v[c];
        v[c] = expf(v[c] - mx);
        s += v[c];
    }
    unsigned word = 1u << (Cn + t);   // target one-hot bit
#pragma unroll
    for (int c = 0; c < Cn; ++c) {
        float prob = v[c] / s;
        int pb = (prob > 0.5f) ? 1 : 0;
        word |= (unsigned)pb << c;
        float oh = (c == t) ? 1.0f : 0.0f;
        float d = prob - oh;
        err[(size_t)(b * Cn + c) * HWn + p] = d * d;
    }
    maskw[pix] = word;
    float logp_t = raw_t - mx - logf(s);

    // wave-level OR + CE sum (no barriers), one plain store per wave
    unsigned worw = word;
    for (int o = 32; o > 0; o >>= 1) worw |= __shfl_down(worw, o, 64);
    double ced = (double)logp_t;
    for (int o = 32; o > 0; o >>= 1) ced += __shfl_down(ced, o, 64);
    int lane = threadIdx.x & 63, wv = threadIdx.x >> 6;
    if (lane == 0) {
        blockOr[blockIdx.x * 4 + wv] = worw;   // plain store, zero contention
        cepart[blockIdx.x * 4 + wv] = ced;
    }
}

__device__ __forceinline__ int mask_has_fg(const unsigned int* fgflags, int m) {
    int mm = (m < NPLANE) ? m : m - NPLANE;
    int b = mm / Cn, c = mm % Cn;
    unsigned fg = (m < NPLANE) ? fgflags[b] : fgflags[4 + b];
    return (fg >> c) & 1;
}

// ---------------------------------------------------------------------------
// Kernel C: segmented column pass, R11 BYTE-LDS version (the 78.4 us champion;
// R12/R13's packed-u32 variant was the likely 12 us regression - its pk|=
// chain serialized the mask loads). Ungated; rowpass gates correctness.
// Block NJOB*SEG does the fgflags reduction (stream order covers the dep).
// ---------------------------------------------------------------------------
constexpr int SEG  = 4;
constexpr int SEGR = Hn / SEG;   // 64
constexpr int STRb = 68;         // LDS byte stride per thread (17 words, coprime banks)

__global__ void colpass_kernel(const unsigned int* __restrict__ maskw,
                               const unsigned int* __restrict__ blockOr,
                               unsigned short* __restrict__ gcol,
                               unsigned int* __restrict__ fgflags) {
    int blk = blockIdx.x;         // 0..768
    int tid = threadIdx.x;
    int lane = tid & 63, wv = tid >> 6;
    if (blk == NJOB * SEG) {
        unsigned acc = 0;
#pragma unroll
        for (int k = 0; k < 16; ++k) acc |= blockOr[wv * 1024 + k * 64 + lane];
        for (int o = 32; o > 0; o >>= 1) acc |= __shfl_down(acc, o, 64);
        if (lane == 0) {
            fgflags[wv] = acc & 0xFFFu;
            fgflags[4 + wv] = acc >> Cn;
        }
        return;
    }
    int jb = blk >> 2;            // job 0..191
    int cg = blk & 3;             // column group
    int m  = (jb < NMASK) ? jb : jb - NMASK;
    int mm = (m < NPLANE) ? m : m - NPLANE;
    int b = mm / Cn, c = mm % Cn;
    unsigned bit = (m < NPLANE) ? (unsigned)c : (unsigned)(Cn + c);
    unsigned inv = (jb < NMASK) ? 1u : 0u;  // feature = !maskbit for edt(mask)
    int s  = wv;                  // segment 0..3 (uniform per wave)
    int jl = lane;
    int j  = cg * 64 + jl;
    int r0 = s * SEGR;
    const unsigned int* mp = maskw + (size_t)b * HWn;
    unsigned short* gp = gcol + (size_t)jb * HWn;

    __shared__ unsigned char ldsF[256 * STRb];
    __shared__ unsigned char ldsB[256 * STRb];
    __shared__ float eF[256], eB[256];

    unsigned b0 = 0, b1 = 0;
    float cd = LARGEf;
    for (int i = 0; i < SEGR; ++i) {
        unsigned w = mp[(r0 + i) * Wn + j];
        unsigned f = ((w >> bit) & 1u) ^ inv;
        if (i < 32) b0 |= f << i; else b1 |= f << (i - 32);
        cd = f ? 0.f : fminf(cd + 1.f, LARGEf);
        ldsF[tid * STRb + i] = (unsigned char)fminf(cd, 255.f);   // <=63 or 255
    }
    eF[tid] = cd;
    cd = LARGEf;
    for (int i = SEGR - 1; i >= 0; --i) {
        unsigned f = ((i < 32) ? (b0 >> i) : (b1 >> (i - 32))) & 1u;
        cd = f ? 0.f : fminf(cd + 1.f, LARGEf);
        ldsB[tid * STRb + i] = (unsigned char)fminf(cd, 255.f);
    }
    eB[tid] = cd;
    __syncthreads();
    float x = LARGEf;                         // fwd inflow to my segment
    for (int sp = 0; sp < s; ++sp)
        x = fminf(eF[sp * 64 + jl], fminf(x + (float)SEGR, LARGEf));
    float y = LARGEf;                         // bwd inflow from below
    for (int sp = SEG - 1; sp > s; --sp)
        y = fminf(eB[sp * 64 + jl], fminf(y + (float)SEGR, LARGEf));
#pragma unroll 8
    for (int i = 0; i < SEGR; ++i) {
        unsigned char uf = ldsF[tid * STRb + i];
        unsigned char ub = ldsB[tid * STRb + i];
        float lf = (uf == 255u) ? LARGEf : (float)uf;
        float lb = (ub == 255u) ? LARGEf : (float)ub;
        float f = fminf(lf, fminf(x + (float)(i + 1), LARGEf));
        float w = fminf(lb, fminf(y + (float)(SEGR - i), LARGEf));
        float g = fminf(f, w);
        gp[(r0 + i) * Wn + j] = (g >= LARGEf) ? SENT : (unsigned short)g;
    }
}

// ---------------------------------------------------------------------------
// Kernel D: R11's wave-per-row FLOAT row pass (champion) + err prefetch.
// Block = 4 rows (1 wave each, private LDS slice). Lane scans 4 columns
// (l+64g) in one fused loop: 4 independent fmin chains, 16 independent LDS
// reads/iter. X=fl(1e12) padding -> unconditional loads (exact). The err row
// is prefetched into registers BEFORE the barrier so its HBM latency hides
// under the scan. Epilogue: f64 wave reduce, one partial per row.
// ---------------------------------------------------------------------------
constexpr int RPAD = 256;
constexpr int NROWBLK = NMASK * Hn;   // 24576 row-jobs
constexpr int RPB = 4;                // rows per block (one per wave)

__device__ __forceinline__ void scan4(const float* __restrict__ base, float m[4]) {
    float k2 = 1.f;                    // k^2
    for (int k = 1; k < Wn; k += 2) {
        float mx = fmaxf(fmaxf(m[0], m[1]), fmaxf(m[2], m[3]));
        if (k2 >= mx) break;
        float k2b = k2 + (float)(2 * k + 1);   // (k+1)^2
#pragma unroll
        for (int g = 0; g < 4; ++g) {
            const float* p = base + 64 * g;
            m[g] = fminf(m[g], k2  + p[-k]);
            m[g] = fminf(m[g], k2b + p[-k - 1]);
            m[g] = fminf(m[g], k2  + p[k]);
            m[g] = fminf(m[g], k2b + p[k + 1]);
        }
        k2 = k2b + (float)(2 * k + 3);         // (k+2)^2
    }
}

__global__ void rowpass_kernel(const unsigned short* __restrict__ gcol,
                               const float* __restrict__ err,
                               const unsigned int* __restrict__ fgflags,
                               double* __restrict__ partials) {
    int blk = blockIdx.x;                 // 0..6143
    int tid = threadIdx.x;
    int lane = tid & 63, w = tid >> 6;
    int m = (blk * RPB) >> 8;             // plane (uniform: 4 rows never straddle)
    if (!mask_has_fg(fgflags, m)) {
        if (tid < RPB) partials[blk * RPB + tid] = 0.0;
        return;                           // uniform exit (no barrier divergence)
    }
    int job = blk * RPB + w;              // this wave's row-job
    int i = job & (Hn - 1);               // row
    const float X = 1e12f;                // == fl(1e6f*1e6f)
    __shared__ float lds[RPB][2][Wn + 2 * RPAD];
    float* rA = lds[w][0];
    float* rB = lds[w][1];

    // prefetch err row (consumed after the scan; latency hides under it)
    int ep = (m < NPLANE) ? m : m - NPLANE;
    const float* epr = err + (size_t)ep * HWn + i * Wn;
    float e0 = epr[lane], e1 = epr[lane + 64];
    float e2 = epr[lane + 128], e3 = epr[lane + 192];

    // stage: lane covers cols 4*lane..4*lane+3 (8B gcol loads, b128 LDS writes)
    const unsigned short* rp = gcol + (size_t)m * HWn + i * Wn;            // edt(mask)
    const unsigned short* rq = gcol + (size_t)(m + NMASK) * HWn + i * Wn;  // edt(~mask)
    ushort4 ua = ((const ushort4*)rp)[lane];
    ushort4 ub = ((const ushort4*)rq)[lane];
    float4 fa, fb;
    fa.x = (ua.x == SENT) ? X : (float)((int)ua.x * (int)ua.x);
    fa.y = (ua.y == SENT) ? X : (float)((int)ua.y * (int)ua.y);
    fa.z = (ua.z == SENT) ? X : (float)((int)ua.z * (int)ua.z);
    fa.w = (ua.w == SENT) ? X : (float)((int)ua.w * (int)ua.w);
    fb.x = (ub.x == SENT) ? X : (float)((int)ub.x * (int)ub.x);
    fb.y = (ub.y == SENT) ? X : (float)((int)ub.y * (int)ub.y);
    fb.z = (ub.z == SENT) ? X : (float)((int)ub.z * (int)ub.z);
    fb.w = (ub.w == SENT) ? X : (float)((int)ub.w * (int)ub.w);
    float4 xv = make_float4(X, X, X, X);
    ((float4*)rA)[lane] = xv;                       // left pad [0..255]
    ((float4*)(rA + RPAD))[lane] = fa;              // data
    ((float4*)(rA + RPAD + Wn))[lane] = xv;         // right pad
    ((float4*)rB)[lane] = xv;
    ((float4*)(rB + RPAD))[lane] = fb;
    ((float4*)(rB + RPAD + Wn))[lane] = xv;
    __syncthreads();                      // uniform arrival (stage is data-indep)

    // scan: lane's 4 columns are lane + 64g
    float mA[4], mB[4];
#pragma unroll
    for (int g = 0; g < 4; ++g) {
        mA[g] = rA[RPAD + lane + 64 * g];
        mB[g] = rB[RPAD + lane + 64 * g];
    }
    scan4(rA + RPAD + lane, mA);
    scan4(rB + RPAD + lane, mB);

    // loss: field = sqrt(mA)+sqrt(mB); dot with prefetched err values
    float ev[4] = {e0, e1, e2, e3};
    double v = 0.0;
#pragma unroll
    for (int g = 0; g < 4; ++g) {
        float f = sqrtf(mA[g]) + sqrtf(mB[g]);
        v += (double)(ev[g] * (f * f));
    }
    for (int o = 32; o > 0; o >>= 1) v += __shfl_down(v, o, 64);
    if (lane == 0) partials[job] = v;
}

// ---------------------------------------------------------------------------
// Kernel F: final reduction -> scalar (1024 threads)
// ---------------------------------------------------------------------------
__global__ void final_kernel(const double* __restrict__ partials,
                             const double* __restrict__ cepart,
                             float* __restrict__ out) {
    int tid = threadIdx.x;
    double a = 0.0, ce = 0.0;
    for (int idx = tid; idx < NROWBLK; idx += 1024) a += partials[idx];
    for (int idx = tid; idx < 4096; idx += 1024) ce += cepart[idx];
    __shared__ double sa[1024], sc[1024];
    sa[tid] = a; sc[tid] = ce;
    __syncthreads();
    for (int s = 512; s > 0; s >>= 1) {
        if (tid < s) { sa[tid] += sa[tid + s]; sc[tid] += sc[tid + s]; }
        __syncthreads();
    }
    if (tid == 0) {
        double loss_sum = sa[0] / (double)NPIX;        // sum_c mean_{b,h,w}
        double cem = -sc[0] / (double)NPIX;            // ce
        double res = loss_sum / (double)Cn / (double)Bn / 3.0 + cem;
        out[0] = (float)res;
    }
}

// ---------------------------------------------------------------------------
extern "C" void kernel_launch(void* const* d_in, const int* in_sizes, int n_in,
                              void* d_out, int out_size, void* d_ws, size_t ws_size,
                              hipStream_t stream) {
    const float* pred  = (const float*)d_in[0];
    const int* target  = (const int*)d_in[1];
    float* out = (float*)d_out;
    char* ws = (char*)d_ws;

    // workspace layout (~40 MB total)
    unsigned int* maskw = (unsigned int*)ws;                         // 1 MB
    size_t off = (size_t)NPIX * 4;
    float* err = (float*)(ws + off);                                 // 12.6 MB
    off += (size_t)NPLANE * HWn * 4;
    unsigned short* gcol = (unsigned short*)(ws + off);              // 25.2 MB
    off += (size_t)NJOB * HWn * 2;
    unsigned int* fgflags = (unsigned int*)(ws + off);               // 8 u32 (pad 512)
    off += 512;
    unsigned int* blockOr = (unsigned int*)(ws + off);               // 4096*4
    off += 4096 * 4;
    double* partials = (double*)(ws + off);                          // 24576*8
    off += (size_t)NROWBLK * 8;
    double* cepart = (double*)(ws + off);                            // 4096*8

    masks_kernel<<<NPIX / 256, 256, 0, stream>>>(pred, target, maskw, err,
                                                 blockOr, cepart);
    colpass_kernel<<<NJOB * SEG + 1, 256, 0, stream>>>(maskw, blockOr, gcol, fgflags);
    rowpass_kernel<<<NROWBLK / RPB, 256, 0, stream>>>(gcol, err, fgflags, partials);
    final_kernel<<<1, 1024, 0, stream>>>(partials, cepart, out);
}

// Round 15
// 66.207 us; speedup vs baseline: 1.3646x; 1.1910x over previous
//
#include <hip/hip_runtime.h>
#include <math.h>

// Problem constants (match reference)
constexpr int Bn = 4, Cn = 12, Hn = 256, Wn = 256;
constexpr int HWn  = Hn * Wn;        // 65536
constexpr int NPIX = Bn * HWn;       // 262144
constexpr int NPLANE = Bn * Cn;      // 48 (b,c) planes
constexpr int NMASK = 2 * NPLANE;    // 96 masks (48 pred + 48 target)
constexpr int NJOB  = 2 * NMASK;     // 192 EDT jobs (edt(mask), edt(~mask))
constexpr float LARGEf = 1.0e6f;
constexpr unsigned short SENT = 65535;

// fgflags layout: [0..3] = pred fg bitmask per batch (bit c), [4..7] = tgt fg

// ---------------------------------------------------------------------------
// Kernel A: per-pixel softmax -> bit-packed masks word (bits 0..11 pred>0.5,
// bits 12..23 target one-hot), err = (prob-onehot)^2 per channel, CE partial
// per wave, per-wave OR word plain-stored (no contended atomics).
// ---------------------------------------------------------------------------
__global__ void masks_kernel(const float* __restrict__ pred,
                             const int* __restrict__ target,
                             unsigned int* __restrict__ maskw,
                             float* __restrict__ err,
                             unsigned int* __restrict__ blockOr,
                             double* __restrict__ cepart) {
    int pix = blockIdx.x * blockDim.x + threadIdx.x;   // grid = NPIX exactly
    int b = pix >> 16;            // / HW (each block lies within one b)
    int p = pix & (HWn - 1);
    float v[Cn];
    float mx = -3.4e38f;
#pragma unroll
    for (int c = 0; c < Cn; ++c) {
        v[c] = pred[(size_t)(b * Cn + c) * HWn + p];
        mx = fmaxf(mx, v[c]);
    }
    int t = target[pix];
    float raw_t = 0.f, s = 0.f;
#pragma unroll
    for (int c = 0; c < Cn; ++c) {
        if (c == t) raw_t = v[c];
        v[c] = expf(v[c] - mx);
        s += v[c];
    }
    unsigned word = 1u << (Cn + t);   // target one-hot bit
#pragma unroll
    for (int c = 0; c < Cn; ++c) {
        float prob = v[c] / s;
        int pb = (prob > 0.5f) ? 1 : 0;
        word |= (unsigned)pb << c;
        float oh = (c == t) ? 1.0f : 0.0f;
        float d = prob - oh;
        err[(size_t)(b * Cn + c) * HWn + p] = d * d;
    }
    maskw[pix] = word;
    float logp_t = raw_t - mx - logf(s);

    // wave-level OR + CE sum (no barriers), one plain store per wave
    unsigned worw = word;
    for (int o = 32; o > 0; o >>= 1) worw |= __shfl_down(worw, o, 64);
    double ced = (double)logp_t;
    for (int o = 32; o > 0; o >>= 1) ced += __shfl_down(ced, o, 64);
    int lane = threadIdx.x & 63, wv = threadIdx.x >> 6;
    if (lane == 0) {
        blockOr[blockIdx.x * 4 + wv] = worw;   // plain store, zero contention
        cepart[blockIdx.x * 4 + wv] = ced;
    }
}

__device__ __forceinline__ int mask_has_fg(const unsigned int* fgflags, int m) {
    int mm = (m < NPLANE) ? m : m - NPLANE;
    int b = mm / Cn, c = mm % Cn;
    unsigned fg = (m < NPLANE) ? fgflags[b] : fgflags[4 + b];
    return (fg >> c) & 1;
}

// ---------------------------------------------------------------------------
// Kernel C (v2): segmented column pass, BOTH polarities fused per block
// (one maskw read feeds A = edt(mask), feature=~mask, and B = edt(~mask),
// feature=mask; two interleaved scan chains = 2-way ILP on the serial
// recurrence). Backward scan is register-resident (fused with the output
// loop, exact same recurrence) -> no ldsB. Segment end-states via clz/ctz
// (provably equal to the saturating-scan end states; LARGE when no bit).
// Block NMASK*4 does the fgflags reduction (stream order covers the dep).
// ---------------------------------------------------------------------------
constexpr int SEG  = 4;
constexpr int SEGR = Hn / SEG;   // 64
constexpr int STRb = 68;         // LDS byte stride per thread (17 words, coprime banks)

__global__ void colpass_kernel(const unsigned int* __restrict__ maskw,
                               const unsigned int* __restrict__ blockOr,
                               unsigned short* __restrict__ gcol,
                               unsigned int* __restrict__ fgflags) {
    int blk = blockIdx.x;         // 0..384
    int tid = threadIdx.x;
    int lane = tid & 63, wv = tid >> 6;
    if (blk == NMASK * 4) {
        unsigned acc = 0;
#pragma unroll
        for (int k = 0; k < 16; ++k) acc |= blockOr[wv * 1024 + k * 64 + lane];
        for (int o = 32; o > 0; o >>= 1) acc |= __shfl_down(acc, o, 64);
        if (lane == 0) {
            fgflags[wv] = acc & 0xFFFu;
            fgflags[4 + wv] = acc >> Cn;
        }
        return;
    }
    int m  = blk >> 2;            // mask plane 0..95
    int cg = blk & 3;             // column group
    int mm = (m < NPLANE) ? m : m - NPLANE;
    int b = mm / Cn, c = mm % Cn;
    unsigned bit = (m < NPLANE) ? (unsigned)c : (unsigned)(Cn + c);
    int s  = wv;                  // segment 0..3 (uniform per wave)
    int jl = lane;
    int j  = cg * 64 + jl;
    int r0 = s * SEGR;
    const unsigned int* mp = maskw + (size_t)b * HWn;
    unsigned short* gpA = gcol + (size_t)m * HWn;             // edt(mask)
    unsigned short* gpB = gcol + (size_t)(m + NMASK) * HWn;   // edt(~mask)

    __shared__ unsigned char ldsFA[256 * STRb];
    __shared__ unsigned char ldsFB[256 * STRb];
    __shared__ float eFA[256], eFB[256], eBA[256], eBB[256];

    // fwd scans (both polarities, interleaved chains); collect mask bits
    unsigned long long vbits = 0ull;   // bit i = mask bit at row r0+i
    float cdA = LARGEf, cdB = LARGEf;
    for (int i = 0; i < SEGR; ++i) {
        unsigned w = mp[(r0 + i) * Wn + j];
        unsigned f = (w >> bit) & 1u;          // mask bit
        vbits |= (unsigned long long)f << i;
        cdA = (!f) ? 0.f : fminf(cdA + 1.f, LARGEf);   // feature A = !mask
        cdB = f ? 0.f : fminf(cdB + 1.f, LARGEf);      // feature B = mask
        ldsFA[tid * STRb + i] = (unsigned char)fminf(cdA, 255.f);
        ldsFB[tid * STRb + i] = (unsigned char)fminf(cdB, 255.f);
    }
    // end states: fwd end = clz (63 - highest set bit), bwd end = ctz
    unsigned long long aBits = ~vbits;         // feature A bits (64 rows)
    eFA[tid] = cdA;                            // == clzll(aBits) when aBits!=0
    eFB[tid] = cdB;
    eBA[tid] = aBits ? (float)__builtin_ctzll(aBits) : LARGEf;
    eBB[tid] = vbits ? (float)__builtin_ctzll(vbits) : LARGEf;
    __syncthreads();
    // inflows
    float xA = LARGEf, xB = LARGEf;            // fwd inflow from earlier segs
    for (int sp = 0; sp < s; ++sp) {
        xA = fminf(eFA[sp * 64 + jl], fminf(xA + (float)SEGR, LARGEf));
        xB = fminf(eFB[sp * 64 + jl], fminf(xB + (float)SEGR, LARGEf));
    }
    float yA = LARGEf, yB = LARGEf;            // bwd inflow from later segs
    for (int sp = SEG - 1; sp > s; --sp) {
        yA = fminf(eBA[sp * 64 + jl], fminf(yA + (float)SEGR, LARGEf));
        yB = fminf(eBB[sp * 64 + jl], fminf(yB + (float)SEGR, LARGEf));
    }
    // output loop, backward: bwd locals as register chains (exact recurrence)
    float cA = LARGEf, cB = LARGEf;
    for (int i = SEGR - 1; i >= 0; --i) {
        unsigned f = (unsigned)((vbits >> i) & 1ull);
        cA = (!f) ? 0.f : fminf(cA + 1.f, LARGEf);
        cB = f ? 0.f : fminf(cB + 1.f, LARGEf);
        unsigned char ufA = ldsFA[tid * STRb + i];
        unsigned char ufB = ldsFB[tid * STRb + i];
        float lfA = (ufA == 255u) ? LARGEf : (float)ufA;
        float lfB = (ufB == 255u) ? LARGEf : (float)ufB;
        float fA = fminf(lfA, fminf(xA + (float)(i + 1), LARGEf));
        float wA = fminf(cA,  fminf(yA + (float)(SEGR - i), LARGEf));
        float gA = fminf(fA, wA);
        float fB = fminf(lfB, fminf(xB + (float)(i + 1), LARGEf));
        float wB = fminf(cB,  fminf(yB + (float)(SEGR - i), LARGEf));
        float gB = fminf(fB, wB);
        gpA[(r0 + i) * Wn + j] = (gA >= LARGEf) ? SENT : (unsigned short)gA;
        gpB[(r0 + i) * Wn + j] = (gB >= LARGEf) ? SENT : (unsigned short)gB;
    }
}

// ---------------------------------------------------------------------------
// Kernel D: R11's wave-per-row FLOAT row pass (champion) + err prefetch.
// Block = 4 rows (1 wave each, private LDS slice). Lane scans 4 columns
// (l+64g) in one fused loop: 4 independent fmin chains, 16 independent LDS
// reads/iter. X=fl(1e12) padding -> unconditional loads (exact).
// ---------------------------------------------------------------------------
constexpr int RPAD = 256;
constexpr int NROWBLK = NMASK * Hn;   // 24576 row-jobs
constexpr int RPB = 4;                // rows per block (one per wave)

__device__ __forceinline__ void scan4(const float* __restrict__ base, float m[4]) {
    float k2 = 1.f;                    // k^2
    for (int k = 1; k < Wn; k += 2) {
        float mx = fmaxf(fmaxf(m[0], m[1]), fmaxf(m[2], m[3]));
        if (k2 >= mx) break;
        float k2b = k2 + (float)(2 * k + 1);   // (k+1)^2
#pragma unroll
        for (int g = 0; g < 4; ++g) {
            const float* p = base + 64 * g;
            m[g] = fminf(m[g], k2  + p[-k]);
            m[g] = fminf(m[g], k2b + p[-k - 1]);
            m[g] = fminf(m[g], k2  + p[k]);
            m[g] = fminf(m[g], k2b + p[k + 1]);
        }
        k2 = k2b + (float)(2 * k + 3);         // (k+2)^2
    }
}

__global__ void rowpass_kernel(const unsigned short* __restrict__ gcol,
                               const float* __restrict__ err,
                               const unsigned int* __restrict__ fgflags,
                               double* __restrict__ partials) {
    int blk = blockIdx.x;                 // 0..6143
    int tid = threadIdx.x;
    int lane = tid & 63, w = tid >> 6;
    int m = (blk * RPB) >> 8;             // plane (uniform: 4 rows never straddle)
    if (!mask_has_fg(fgflags, m)) {
        if (tid < RPB) partials[blk * RPB + tid] = 0.0;
        return;                           // uniform exit (no barrier divergence)
    }
    int job = blk * RPB + w;              // this wave's row-job
    int i = job & (Hn - 1);               // row
    const float X = 1e12f;                // == fl(1e6f*1e6f)
    __shared__ float lds[RPB][2][Wn + 2 * RPAD];
    float* rA = lds[w][0];
    float* rB = lds[w][1];

    // prefetch err row (consumed after the scan; latency hides under it)
    int ep = (m < NPLANE) ? m : m - NPLANE;
    const float* epr = err + (size_t)ep * HWn + i * Wn;
    float e0 = epr[lane], e1 = epr[lane + 64];
    float e2 = epr[lane + 128], e3 = epr[lane + 192];

    // stage: lane covers cols 4*lane..4*lane+3 (8B gcol loads, b128 LDS writes)
    const unsigned short* rp = gcol + (size_t)m * HWn + i * Wn;            // edt(mask)
    const unsigned short* rq = gcol + (size_t)(m + NMASK) * HWn + i * Wn;  // edt(~mask)
    ushort4 ua = ((const ushort4*)rp)[lane];
    ushort4 ub = ((const ushort4*)rq)[lane];
    float4 fa, fb;
    fa.x = (ua.x == SENT) ? X : (float)((int)ua.x * (int)ua.x);
    fa.y = (ua.y == SENT) ? X : (float)((int)ua.y * (int)ua.y);
    fa.z = (ua.z == SENT) ? X : (float)((int)ua.z * (int)ua.z);
    fa.w = (ua.w == SENT) ? X : (float)((int)ua.w * (int)ua.w);
    fb.x = (ub.x == SENT) ? X : (float)((int)ub.x * (int)ub.x);
    fb.y = (ub.y == SENT) ? X : (float)((int)ub.y * (int)ub.y);
    fb.z = (ub.z == SENT) ? X : (float)((int)ub.z * (int)ub.z);
    fb.w = (ub.w == SENT) ? X : (float)((int)ub.w * (int)ub.w);
    float4 xv = make_float4(X, X, X, X);
    ((float4*)rA)[lane] = xv;                       // left pad [0..255]
    ((float4*)(rA + RPAD))[lane] = fa;              // data
    ((float4*)(rA + RPAD + Wn))[lane] = xv;         // right pad
    ((float4*)rB)[lane] = xv;
    ((float4*)(rB + RPAD))[lane] = fb;
    ((float4*)(rB + RPAD + Wn))[lane] = xv;
    __syncthreads();                      // uniform arrival (stage is data-indep)

    // scan: lane's 4 columns are lane + 64g
    float mA[4], mB[4];
#pragma unroll
    for (int g = 0; g < 4; ++g) {
        mA[g] = rA[RPAD + lane + 64 * g];
        mB[g] = rB[RPAD + lane + 64 * g];
    }
    scan4(rA + RPAD + lane, mA);
    scan4(rB + RPAD + lane, mB);

    // loss: field = sqrt(mA)+sqrt(mB); dot with prefetched err values
    float ev[4] = {e0, e1, e2, e3};
    double v = 0.0;
#pragma unroll
    for (int g = 0; g < 4; ++g) {
        float f = sqrtf(mA[g]) + sqrtf(mB[g]);
        v += (double)(ev[g] * (f * f));
    }
    for (int o = 32; o > 0; o >>= 1) v += __shfl_down(v, o, 64);
    if (lane == 0) partials[job] = v;
}

// ---------------------------------------------------------------------------
// Kernel F: final reduction -> scalar (1024 threads)
// ---------------------------------------------------------------------------
__global__ void final_kernel(const double* __restrict__ partials,
                             const double* __restrict__ cepart,
                             float* __restrict__ out) {
    int tid = threadIdx.x;
    double a = 0.0, ce = 0.0;
    for (int idx = tid; idx < NROWBLK; idx += 1024) a += partials[idx];
    for (int idx = tid; idx < 4096; idx += 1024) ce += cepart[idx];
    __shared__ double sa[1024], sc[1024];
    sa[tid] = a; sc[tid] = ce;
    __syncthreads();
    for (int s = 512; s > 0; s >>= 1) {
        if (tid < s) { sa[tid] += sa[tid + s]; sc[tid] += sc[tid + s]; }
        __syncthreads();
    }
    if (tid == 0) {
        double loss_sum = sa[0] / (double)NPIX;        // sum_c mean_{b,h,w}
        double cem = -sc[0] / (double)NPIX;            // ce
        double res = loss_sum / (double)Cn / (double)Bn / 3.0 + cem;
        out[0] = (float)res;
    }
}

// ---------------------------------------------------------------------------
extern "C" void kernel_launch(void* const* d_in, const int* in_sizes, int n_in,
                              void* d_out, int out_size, void* d_ws, size_t ws_size,
                              hipStream_t stream) {
    const float* pred  = (const float*)d_in[0];
    const int* target  = (const int*)d_in[1];
    float* out = (float*)d_out;
    char* ws = (char*)d_ws;

    // workspace layout (~40 MB total)
    unsigned int* maskw = (unsigned int*)ws;                         // 1 MB
    size_t off = (size_t)NPIX * 4;
    float* err = (float*)(ws + off);                                 // 12.6 MB
    off += (size_t)NPLANE * HWn * 4;
    unsigned short* gcol = (unsigned short*)(ws + off);              // 25.2 MB
    off += (size_t)NJOB * HWn * 2;
    unsigned int* fgflags = (unsigned int*)(ws + off);               // 8 u32 (pad 512)
    off += 512;
    unsigned int* blockOr = (unsigned int*)(ws + off);               // 4096*4
    off += 4096 * 4;
    double* partials = (double*)(ws + off);                          // 24576*8
    off += (size_t)NROWBLK * 8;
    double* cepart = (double*)(ws + off);                            // 4096*8

    masks_kernel<<<NPIX / 256, 256, 0, stream>>>(pred, target, maskw, err,
                                                 blockOr, cepart);
    colpass_kernel<<<NMASK * 4 + 1, 256, 0, stream>>>(maskw, blockOr, gcol, fgflags);
    rowpass_kernel<<<NROWBLK / RPB, 256, 0, stream>>>(gcol, err, fgflags, partials);
    final_kernel<<<1, 1024, 0, stream>>>(partials, cepart, out);
}

// Round 16
// 65.427 us; speedup vs baseline: 1.3809x; 1.0119x over previous
//
#include <hip/hip_runtime.h>
#include <math.h>

// Problem constants (match reference)
constexpr int Bn = 4, Cn = 12, Hn = 256, Wn = 256;
constexpr int HWn  = Hn * Wn;        // 65536
constexpr int NPIX = Bn * HWn;       // 262144
constexpr int NPLANE = Bn * Cn;      // 48 (b,c) planes
constexpr int NMASK = 2 * NPLANE;    // 96 masks (48 pred + 48 target)
constexpr int NJOB  = 2 * NMASK;     // 192 EDT jobs (edt(mask), edt(~mask))
constexpr float LARGEf = 1.0e6f;

// fgflags layout: [0..3] = pred fg bitmask per batch (bit c), [4..7] = tgt fg
// colmask layout: [jb][8 u32] bit set = column EMPTY (all-sentinel)

// ---------------------------------------------------------------------------
// Kernel A: per-pixel softmax -> bit-packed masks word (bits 0..11 pred>0.5,
// bits 12..23 target one-hot), err = (prob-onehot)^2 per channel, CE partial
// per wave, per-wave OR word plain-stored (no contended atomics).
// ---------------------------------------------------------------------------
__global__ void masks_kernel(const float* __restrict__ pred,
                             const int* __restrict__ target,
                             unsigned int* __restrict__ maskw,
                             float* __restrict__ err,
                             unsigned int* __restrict__ blockOr,
                             double* __restrict__ cepart) {
    int pix = blockIdx.x * blockDim.x + threadIdx.x;   // grid = NPIX exactly
    int b = pix >> 16;            // / HW (each block lies within one b)
    int p = pix & (HWn - 1);
    float v[Cn];
    float mx = -3.4e38f;
#pragma unroll
    for (int c = 0; c < Cn; ++c) {
        v[c] = pred[(size_t)(b * Cn + c) * HWn + p];
        mx = fmaxf(mx, v[c]);
    }
    int t = target[pix];
    float raw_t = 0.f, s = 0.f;
#pragma unroll
    for (int c = 0; c < Cn; ++c) {
        if (c == t) raw_t = v[c];
        v[c] = expf(v[c] - mx);
        s += v[c];
    }
    unsigned word = 1u << (Cn + t);   // target one-hot bit
#pragma unroll
    for (int c = 0; c < Cn; ++c) {
        float prob = v[c] / s;
        int pb = (prob > 0.5f) ? 1 : 0;
        word |= (unsigned)pb << c;
        float oh = (c == t) ? 1.0f : 0.0f;
        float d = prob - oh;
        err[(size_t)(b * Cn + c) * HWn + p] = d * d;
    }
    maskw[pix] = word;
    float logp_t = raw_t - mx - logf(s);

    // wave-level OR + CE sum (no barriers), one plain store per wave
    unsigned worw = word;
    for (int o = 32; o > 0; o >>= 1) worw |= __shfl_down(worw, o, 64);
    double ced = (double)logp_t;
    for (int o = 32; o > 0; o >>= 1) ced += __shfl_down(ced, o, 64);
    int lane = threadIdx.x & 63, wv = threadIdx.x >> 6;
    if (lane == 0) {
        blockOr[blockIdx.x * 4 + wv] = worw;   // plain store, zero contention
        cepart[blockIdx.x * 4 + wv] = ced;
    }
}

__device__ __forceinline__ int mask_has_fg(const unsigned int* fgflags, int m) {
    int mm = (m < NPLANE) ? m : m - NPLANE;
    int b = mm / Cn, c = mm % Cn;
    unsigned fg = (m < NPLANE) ? fgflags[b] : fgflags[4 + b];
    return (fg >> c) & 1;
}

// ---------------------------------------------------------------------------
// Kernel C (v3): fused-polarity segmented column pass (R15 structure) with
// u8 output + per-column empty masks. All finite column distances are <=255
// (exact in u8); a column is all-sentinel iff it has no feature -> 1 bit per
// column per polarity (LDS AND across segments + ballot in wave 0).
// Block NMASK*4 does the fgflags reduction.
// ---------------------------------------------------------------------------
constexpr int SEG  = 4;
constexpr int SEGR = Hn / SEG;   // 64
constexpr int STRb = 68;         // LDS byte stride per thread (17 words, coprime banks)

__global__ void colpass_kernel(const unsigned int* __restrict__ maskw,
                               const unsigned int* __restrict__ blockOr,
                               unsigned char* __restrict__ gcol,
                               unsigned int* __restrict__ colmask,
                               unsigned int* __restrict__ fgflags) {
    int blk = blockIdx.x;         // 0..384
    int tid = threadIdx.x;
    int lane = tid & 63, wv = tid >> 6;
    if (blk == NMASK * 4) {
        unsigned acc = 0;
#pragma unroll
        for (int k = 0; k < 16; ++k) acc |= blockOr[wv * 1024 + k * 64 + lane];
        for (int o = 32; o > 0; o >>= 1) acc |= __shfl_down(acc, o, 64);
        if (lane == 0) {
            fgflags[wv] = acc & 0xFFFu;
            fgflags[4 + wv] = acc >> Cn;
        }
        return;
    }
    int m  = blk >> 2;            // mask plane 0..95
    int cg = blk & 3;             // column group
    int mm = (m < NPLANE) ? m : m - NPLANE;
    int b = mm / Cn, c = mm % Cn;
    unsigned bit = (m < NPLANE) ? (unsigned)c : (unsigned)(Cn + c);
    int s  = wv;                  // segment 0..3 (uniform per wave)
    int jl = lane;
    int j  = cg * 64 + jl;
    int r0 = s * SEGR;
    const unsigned int* mp = maskw + (size_t)b * HWn;
    unsigned char* gpA = gcol + (size_t)m * HWn;              // edt(mask)
    unsigned char* gpB = gcol + (size_t)(m + NMASK) * HWn;    // edt(~mask)

    __shared__ unsigned char ldsFA[256 * STRb];
    __shared__ unsigned char ldsFB[256 * STRb];
    __shared__ float eFA[256], eFB[256], eBA[256], eBB[256];
    __shared__ unsigned char segEmptyA[256], segEmptyB[256];

    // fwd scans (both polarities, interleaved chains); collect mask bits
    unsigned long long vbits = 0ull;   // bit i = mask bit at row r0+i
    float cdA = LARGEf, cdB = LARGEf;
    for (int i = 0; i < SEGR; ++i) {
        unsigned w = mp[(r0 + i) * Wn + j];
        unsigned f = (w >> bit) & 1u;          // mask bit
        vbits |= (unsigned long long)f << i;
        cdA = (!f) ? 0.f : fminf(cdA + 1.f, LARGEf);   // feature A = !mask
        cdB = f ? 0.f : fminf(cdB + 1.f, LARGEf);      // feature B = mask
        ldsFA[tid * STRb + i] = (unsigned char)fminf(cdA, 255.f);
        ldsFB[tid * STRb + i] = (unsigned char)fminf(cdB, 255.f);
    }
    unsigned long long aBits = ~vbits;         // feature A bits (64 rows)
    eFA[tid] = cdA;
    eFB[tid] = cdB;
    eBA[tid] = aBits ? (float)__builtin_ctzll(aBits) : LARGEf;
    eBB[tid] = vbits ? (float)__builtin_ctzll(vbits) : LARGEf;
    segEmptyA[tid] = (aBits == 0ull) ? 1 : 0;  // no A-feature in this segment
    segEmptyB[tid] = (vbits == 0ull) ? 1 : 0;
    __syncthreads();
    // per-column empty masks (wave 0): AND across 4 segments, ballot, store
    if (s == 0) {
        int emA = segEmptyA[jl] & segEmptyA[64 + jl] & segEmptyA[128 + jl] & segEmptyA[192 + jl];
        int emB = segEmptyB[jl] & segEmptyB[64 + jl] & segEmptyB[128 + jl] & segEmptyB[192 + jl];
        unsigned long long ba = __ballot(emA);
        unsigned long long bb = __ballot(emB);
        if (jl == 0) {
            colmask[m * 8 + cg * 2]                 = (unsigned)ba;
            colmask[m * 8 + cg * 2 + 1]             = (unsigned)(ba >> 32);
            colmask[(m + NMASK) * 8 + cg * 2]       = (unsigned)bb;
            colmask[(m + NMASK) * 8 + cg * 2 + 1]   = (unsigned)(bb >> 32);
        }
    }
    // inflows
    float xA = LARGEf, xB = LARGEf;            // fwd inflow from earlier segs
    for (int sp = 0; sp < s; ++sp) {
        xA = fminf(eFA[sp * 64 + jl], fminf(xA + (float)SEGR, LARGEf));
        xB = fminf(eFB[sp * 64 + jl], fminf(xB + (float)SEGR, LARGEf));
    }
    float yA = LARGEf, yB = LARGEf;            // bwd inflow from later segs
    for (int sp = SEG - 1; sp > s; --sp) {
        yA = fminf(eBA[sp * 64 + jl], fminf(yA + (float)SEGR, LARGEf));
        yB = fminf(eBB[sp * 64 + jl], fminf(yB + (float)SEGR, LARGEf));
    }
    // output loop, backward: bwd locals as register chains (exact recurrence)
    float cA = LARGEf, cB = LARGEf;
    for (int i = SEGR - 1; i >= 0; --i) {
        unsigned f = (unsigned)((vbits >> i) & 1ull);
        cA = (!f) ? 0.f : fminf(cA + 1.f, LARGEf);
        cB = f ? 0.f : fminf(cB + 1.f, LARGEf);
        unsigned char ufA = ldsFA[tid * STRb + i];
        unsigned char ufB = ldsFB[tid * STRb + i];
        float lfA = (ufA == 255u) ? LARGEf : (float)ufA;
        float lfB = (ufB == 255u) ? LARGEf : (float)ufB;
        float fA = fminf(lfA, fminf(xA + (float)(i + 1), LARGEf));
        float wA = fminf(cA,  fminf(yA + (float)(SEGR - i), LARGEf));
        float gA = fminf(fA, wA);
        float fB = fminf(lfB, fminf(xB + (float)(i + 1), LARGEf));
        float wB = fminf(cB,  fminf(yB + (float)(SEGR - i), LARGEf));
        float gB = fminf(fB, wB);
        // finite values <= 255 exact in u8; empty columns overridden by colmask
        gpA[(r0 + i) * Wn + j] = (unsigned char)fminf(gA, 255.f);
        gpB[(r0 + i) * Wn + j] = (unsigned char)fminf(gB, 255.f);
    }
}

// ---------------------------------------------------------------------------
// Kernel D: R11's wave-per-row FLOAT row pass + u8 gcol staging via colmask.
// Block = 4 rows (1 wave each, private LDS slice). Lane scans 4 columns
// (l+64g) in one fused loop: 4 independent fmin chains, 16 independent LDS
// reads/iter. X=fl(1e12) padding -> unconditional loads (exact).
// g2 = empty(col) ? 1e12f : (float)(g*g) - identical mapping to the SENT path.
// ---------------------------------------------------------------------------
constexpr int RPAD = 256;
constexpr int NROWBLK = NMASK * Hn;   // 24576 row-jobs
constexpr int RPB = 4;                // rows per block (one per wave)

__device__ __forceinline__ void scan4(const float* __restrict__ base, float m[4]) {
    float k2 = 1.f;                    // k^2
    for (int k = 1; k < Wn; k += 2) {
        float mx = fmaxf(fmaxf(m[0], m[1]), fmaxf(m[2], m[3]));
        if (k2 >= mx) break;
        float k2b = k2 + (float)(2 * k + 1);   // (k+1)^2
#pragma unroll
        for (int g = 0; g < 4; ++g) {
            const float* p = base + 64 * g;
            m[g] = fminf(m[g], k2  + p[-k]);
            m[g] = fminf(m[g], k2b + p[-k - 1]);
            m[g] = fminf(m[g], k2  + p[k]);
            m[g] = fminf(m[g], k2b + p[k + 1]);
        }
        k2 = k2b + (float)(2 * k + 3);         // (k+2)^2
    }
}

__global__ void rowpass_kernel(const unsigned char* __restrict__ gcol,
                               const unsigned int* __restrict__ colmask,
                               const float* __restrict__ err,
                               const unsigned int* __restrict__ fgflags,
                               double* __restrict__ partials) {
    int blk = blockIdx.x;                 // 0..6143
    int tid = threadIdx.x;
    int lane = tid & 63, w = tid >> 6;
    int m = (blk * RPB) >> 8;             // plane (uniform: 4 rows never straddle)
    if (!mask_has_fg(fgflags, m)) {
        if (tid < RPB) partials[blk * RPB + tid] = 0.0;
        return;                           // uniform exit (no barrier divergence)
    }
    int job = blk * RPB + w;              // this wave's row-job
    int i = job & (Hn - 1);               // row
    const float X = 1e12f;                // == fl(1e6f*1e6f)
    __shared__ float lds[RPB][2][Wn + 2 * RPAD];
    float* rA = lds[w][0];
    float* rB = lds[w][1];

    // prefetch err row (consumed after the scan; latency hides under it)
    int ep = (m < NPLANE) ? m : m - NPLANE;
    const float* epr = err + (size_t)ep * HWn + i * Wn;
    float e0 = epr[lane], e1 = epr[lane + 64];
    float e2 = epr[lane + 128], e3 = epr[lane + 192];

    // stage: lane covers cols 4*lane..4*lane+3 (4B u8 loads + colmask nibbles)
    const unsigned char* rp = gcol + (size_t)m * HWn + i * Wn;            // edt(mask)
    const unsigned char* rq = gcol + (size_t)(m + NMASK) * HWn + i * Wn;  // edt(~mask)
    unsigned ua4 = ((const unsigned*)rp)[lane];
    unsigned ub4 = ((const unsigned*)rq)[lane];
    unsigned nibA = (colmask[m * 8 + (lane >> 3)] >> ((lane & 7) * 4)) & 0xFu;
    unsigned nibB = (colmask[(m + NMASK) * 8 + (lane >> 3)] >> ((lane & 7) * 4)) & 0xFu;
    float4 fa, fb;
    {
        unsigned g0 = ua4 & 0xFFu, g1 = (ua4 >> 8) & 0xFFu;
        unsigned g2 = (ua4 >> 16) & 0xFFu, g3 = ua4 >> 24;
        fa.x = (nibA & 1u) ? X : (float)(g0 * g0);
        fa.y = (nibA & 2u) ? X : (float)(g1 * g1);
        fa.z = (nibA & 4u) ? X : (float)(g2 * g2);
        fa.w = (nibA & 8u) ? X : (float)(g3 * g3);
        g0 = ub4 & 0xFFu; g1 = (ub4 >> 8) & 0xFFu;
        g2 = (ub4 >> 16) & 0xFFu; g3 = ub4 >> 24;
        fb.x = (nibB & 1u) ? X : (float)(g0 * g0);
        fb.y = (nibB & 2u) ? X : (float)(g1 * g1);
        fb.z = (nibB & 4u) ? X : (float)(g2 * g2);
        fb.w = (nibB & 8u) ? X : (float)(g3 * g3);
    }
    float4 xv = make_float4(X, X, X, X);
    ((float4*)rA)[lane] = xv;                       // left pad [0..255]
    ((float4*)(rA + RPAD))[lane] = fa;              // data
    ((float4*)(rA + RPAD + Wn))[lane] = xv;         // right pad
    ((float4*)rB)[lane] = xv;
    ((float4*)(rB + RPAD))[lane] = fb;
    ((float4*)(rB + RPAD + Wn))[lane] = xv;
    __syncthreads();                      // uniform arrival (stage is data-indep)

    // scan: lane's 4 columns are lane + 64g
    float mA[4], mB[4];
#pragma unroll
    for (int g = 0; g < 4; ++g) {
        mA[g] = rA[RPAD + lane + 64 * g];
        mB[g] = rB[RPAD + lane + 64 * g];
    }
    scan4(rA + RPAD + lane, mA);
    scan4(rB + RPAD + lane, mB);

    // loss: field = sqrt(mA)+sqrt(mB); dot with prefetched err values
    float ev[4] = {e0, e1, e2, e3};
    double v = 0.0;
#pragma unroll
    for (int g = 0; g < 4; ++g) {
        float f = sqrtf(mA[g]) + sqrtf(mB[g]);
        v += (double)(ev[g] * (f * f));
    }
    for (int o = 32; o > 0; o >>= 1) v += __shfl_down(v, o, 64);
    if (lane == 0) partials[job] = v;
}

// ---------------------------------------------------------------------------
// Kernel F: final reduction -> scalar (1024 threads)
// ---------------------------------------------------------------------------
__global__ void final_kernel(const double* __restrict__ partials,
                             const double* __restrict__ cepart,
                             float* __restrict__ out) {
    int tid = threadIdx.x;
    double a = 0.0, ce = 0.0;
    for (int idx = tid; idx < NROWBLK; idx += 1024) a += partials[idx];
    for (int idx = tid; idx < 4096; idx += 1024) ce += cepart[idx];
    __shared__ double sa[1024], sc[1024];
    sa[tid] = a; sc[tid] = ce;
    __syncthreads();
    for (int s = 512; s > 0; s >>= 1) {
        if (tid < s) { sa[tid] += sa[tid + s]; sc[tid] += sc[tid + s]; }
        __syncthreads();
    }
    if (tid == 0) {
        double loss_sum = sa[0] / (double)NPIX;        // sum_c mean_{b,h,w}
        double cem = -sc[0] / (double)NPIX;            // ce
        double res = loss_sum / (double)Cn / (double)Bn / 3.0 + cem;
        out[0] = (float)res;
    }
}

// ---------------------------------------------------------------------------
extern "C" void kernel_launch(void* const* d_in, const int* in_sizes, int n_in,
                              void* d_out, int out_size, void* d_ws, size_t ws_size,
                              hipStream_t stream) {
    const float* pred  = (const float*)d_in[0];
    const int* target  = (const int*)d_in[1];
    float* out = (float*)d_out;
    char* ws = (char*)d_ws;

    // workspace layout (~27 MB total)
    unsigned int* maskw = (unsigned int*)ws;                         // 1 MB
    size_t off = (size_t)NPIX * 4;
    float* err = (float*)(ws + off);                                 // 12.6 MB
    off += (size_t)NPLANE * HWn * 4;
    unsigned char* gcol = (unsigned char*)(ws + off);                // 12.6 MB (u8)
    off += (size_t)NJOB * HWn;
    unsigned int* colmask = (unsigned int*)(ws + off);               // 192*8 u32 = 6 KB
    off += (size_t)NJOB * 8 * 4;
    unsigned int* fgflags = (unsigned int*)(ws + off);               // 8 u32 (pad 512)
    off += 512;
    unsigned int* blockOr = (unsigned int*)(ws + off);               // 4096*4
    off += 4096 * 4;
    double* partials = (double*)(ws + off);                          // 24576*8
    off += (size_t)NROWBLK * 8;
    double* cepart = (double*)(ws + off);                            // 4096*8

    masks_kernel<<<NPIX / 256, 256, 0, stream>>>(pred, target, maskw, err,
                                                 blockOr, cepart);
    colpass_kernel<<<NMASK * 4 + 1, 256, 0, stream>>>(maskw, blockOr, gcol,
                                                      colmask, fgflags);
    rowpass_kernel<<<NROWBLK / RPB, 256, 0, stream>>>(gcol, colmask, err,
                                                      fgflags, partials);
    final_kernel<<<1, 1024, 0, stream>>>(partials, cepart, out);
}